// Round 9
// baseline (482.685 us; speedup 1.0000x reference)
//
#include <hip/hip_runtime.h>
#include <hip/hip_bf16.h>

#define NNODES 100000
#define NEDGES 1600000
#define NEG_SLOPE 0.2f

#define CHUNK 4096
#define EPT 16                                  // edges per thread in k_lsort
#define NBLK ((NEDGES + CHUNK - 1) / CHUNK)     // 391 sort blocks
#define NB ((NNODES + 255) / 256)               // 391 buckets (256 nodes each)
#define FLATN (NB * NBLK)                       // 152881
#define SCB ((FLATN + 255) / 256)               // 598
#define FCAP 5632                               // bucket entry cap (mean 4092, +24 sigma)

__device__ __forceinline__ float wave_sum64(float v) {
#pragma unroll
    for (int off = 1; off < 64; off <<= 1) v += __shfl_xor(v, off, 64);
    return v;
}

__device__ __forceinline__ int wave_sum64i(int v) {
#pragma unroll
    for (int off = 1; off < 64; off <<= 1) v += __shfl_xor(v, off, 64);
    return v;
}

// pack two f32 -> one uint of 2 bf16 (RNE)
__device__ __forceinline__ unsigned pack_bf2(float a, float b) {
    unsigned ua = __float_as_uint(a), ub = __float_as_uint(b);
    ua = (ua + 0x7FFFu + ((ua >> 16) & 1u)) >> 16;
    ub = (ub + 0x7FFFu + ((ub >> 16) & 1u));
    return ua | (ub & 0xFFFF0000u);
}

__device__ __forceinline__ void unpack_bf8(uint4 w, float* f) {
    f[0] = __uint_as_float(w.x << 16);
    f[1] = __uint_as_float(w.x & 0xFFFF0000u);
    f[2] = __uint_as_float(w.y << 16);
    f[3] = __uint_as_float(w.y & 0xFFFF0000u);
    f[4] = __uint_as_float(w.z << 16);
    f[5] = __uint_as_float(w.z & 0xFFFF0000u);
    f[6] = __uint_as_float(w.w << 16);
    f[7] = __uint_as_float(w.w & 0xFFFF0000u);
}

// ---------------- phase A: per-chunk counting sort by bucket (all-coalesced) ----------------

__global__ __launch_bounds__(256) void k_lsort(const int* __restrict__ src,
                                               const int* __restrict__ dst,
                                               const float* __restrict__ ea,
                                               uint2* __restrict__ tmps,
                                               int* __restrict__ gcnt,
                                               int* __restrict__ lscan,
                                               float* __restrict__ easum) {
    __shared__ uint2 ent[CHUNK];                 // 32 KB
    __shared__ unsigned short perm[CHUNK];       // 8 KB
    __shared__ int hist[NB];
    __shared__ int cur[NB];
    __shared__ float ws[4];
    const int t = threadIdx.x;
    const int j = blockIdx.x;
    const int base = j * CHUNK;
    const int n = min(CHUNK, NEDGES - base);

    for (int b = t; b < NB; b += 256) hist[b] = 0;
    __syncthreads();

    int bkt[EPT];
    float s = 0.f;
#pragma unroll
    for (int k = 0; k < EPT; ++k) {
        const int l = t + k * 256;
        bkt[k] = -1;
        if (l < n) {
            const int i = base + l;
            const int d = dst[i];
            const float e = ea[i];
            const int b = d >> 8;
            bkt[k] = b;
            ent[l] = make_uint2((unsigned)src[i] | ((unsigned)(d & 255) << 17),
                                __float_as_uint(e));
            atomicAdd(&hist[b], 1);
            s += e;
        }
    }
    s = wave_sum64(s);
    if ((t & 63) == 0) ws[t >> 6] = s;
    __syncthreads();
    if (t == 0) atomicAdd(easum, ws[0] + ws[1] + ws[2] + ws[3]);

    // exclusive scan of hist[0..NB) -> cur, wave 0 only (56 lanes x 7 elems)
    if (t < 64) {
        int x[7];
        int run = 0;
#pragma unroll
        for (int q = 0; q < 7; ++q) {
            const int idx = t * 7 + q;
            x[q] = (idx < NB) ? hist[idx] : 0;
            run += x[q];
        }
        int inc = run;
#pragma unroll
        for (int o = 1; o < 64; o <<= 1) {
            int u = __shfl_up(inc, o, 64);
            if (t >= o) inc += u;
        }
        int r = inc - run;   // lane-exclusive
#pragma unroll
        for (int q = 0; q < 7; ++q) {
            const int idx = t * 7 + q;
            if (idx < NB) cur[idx] = r;
            r += x[q];
        }
    }
    __syncthreads();

#pragma unroll
    for (int k = 0; k < EPT; ++k) {
        if (bkt[k] >= 0) {
            const int r = atomicAdd(&cur[bkt[k]], 1);
            perm[r] = (unsigned short)(t + k * 256);
        }
    }
    __syncthreads();

    for (int o = t; o < n; o += 256)
        tmps[base + o] = ent[perm[o]];           // coalesced global write
    for (int b = t; b < NB; b += 256) {
        gcnt[b * NBLK + j] = hist[b];            // bucket-major (for flat scan)
        lscan[j * NB + b] = cur[b] - hist[b];    // local exclusive offset
    }
}

// ---------------- flat exclusive scan of gcnt[FLATN] -> goff ----------------

__global__ __launch_bounds__(256) void k_part2(const int* __restrict__ v, int n,
                                               int* __restrict__ bsum) {
    int i = blockIdx.x * 256 + threadIdx.x;
    int x = (i < n) ? v[i] : 0;
    x = wave_sum64i(x);
    __shared__ int wsh[4];
    if ((threadIdx.x & 63) == 0) wsh[threadIdx.x >> 6] = x;
    __syncthreads();
    if (threadIdx.x == 0) bsum[blockIdx.x] = wsh[0] + wsh[1] + wsh[2] + wsh[3];
}

__global__ __launch_bounds__(1024) void k_scanb2(const int* __restrict__ bsum, int nb,
                                                 int* __restrict__ boff,
                                                 int* __restrict__ rowptr) {
    __shared__ int sh[1024];
    int t = threadIdx.x;
    int v = (t < nb) ? bsum[t] : 0;
    sh[t] = v;
    __syncthreads();
    for (int off = 1; off < 1024; off <<= 1) {
        int u = (t >= off) ? sh[t - off] : 0;
        __syncthreads();
        sh[t] += u;
        __syncthreads();
    }
    if (t < nb) boff[t] = sh[t] - v;
    if (t == 0) rowptr[NNODES] = NEDGES;
}

__global__ __launch_bounds__(256) void k_scanfin2(const int* __restrict__ v, int n,
                                                  const int* __restrict__ boff,
                                                  int* __restrict__ out) {
    int t = threadIdx.x, lane = t & 63, wave = t >> 6;
    int i = blockIdx.x * 256 + t;
    int x = (i < n) ? v[i] : 0;
    int orig = x;
#pragma unroll
    for (int off = 1; off < 64; off <<= 1) {
        int u = __shfl_up(x, off, 64);
        if (lane >= off) x += u;
    }
    __shared__ int wsh[4];
    if (lane == 63) wsh[wave] = x;
    __syncthreads();
    int wexc = 0;
    for (int w = 0; w < wave; ++w) wexc += wsh[w];
    if (i < n) out[i] = boff[blockIdx.x] + wexc + x - orig;
}

// ---------------- phase C: per-bucket gather + LDS counting sort by node ----------------

__global__ __launch_bounds__(256) void k_fsort(const uint2* __restrict__ tmps,
                                               const int* __restrict__ lscan,
                                               const int* __restrict__ goff,
                                               int* __restrict__ rowptr,
                                               uint2* __restrict__ edata) {
    __shared__ uint2 ent[FCAP];                  // 44 KB
    __shared__ unsigned short perm[FCAP];        // 11 KB
    __shared__ int joff[NBLK + 1];
    __shared__ int jsrc[NBLK];
    __shared__ int hist[256];
    __shared__ int cur[256];
    const int b = blockIdx.x;
    const int t = threadIdx.x;
    const int base = goff[b * NBLK];             // bucket base position in edata

    for (int q = t; q < 256; q += 256) hist[q] = 0;
    for (int j = t; j < NBLK; j += 256) {
        joff[j] = goff[b * NBLK + j] - base;
        jsrc[j] = j * CHUNK + lscan[j * NB + b];
    }
    if (t == 0) joff[NBLK] = ((b == NB - 1) ? NEDGES : goff[(b + 1) * NBLK]) - base;
    __syncthreads();
    const int T = min(joff[NBLK], FCAP);

    for (int idx = t; idx < T; idx += 256) {
        int lo = 0, hi = NBLK;
        while (hi - lo > 1) { int mid = (lo + hi) >> 1; if (joff[mid] <= idx) lo = mid; else hi = mid; }
        const uint2 e = tmps[jsrc[lo] + (idx - joff[lo])];   // piecewise-coalesced
        ent[idx] = e;
        atomicAdd(&hist[(e.x >> 17) & 255u], 1);
    }
    __syncthreads();

    // exclusive scan hist[0..256) -> cur, wave 0 (64 lanes x 4)
    if (t < 64) {
        int x[4];
        int run = 0;
#pragma unroll
        for (int q = 0; q < 4; ++q) { x[q] = hist[t * 4 + q]; run += x[q]; }
        int inc = run;
#pragma unroll
        for (int o = 1; o < 64; o <<= 1) {
            int u = __shfl_up(inc, o, 64);
            if (t >= o) inc += u;
        }
        int r = inc - run;
#pragma unroll
        for (int q = 0; q < 4; ++q) { cur[t * 4 + q] = r; r += x[q]; }
    }
    __syncthreads();

    {
        const int i = b * 256 + t;
        if (i < NNODES) rowptr[i] = base + cur[t];
    }
    __syncthreads();    // rowptr reads of cur must complete before rank mutation

    for (int idx = t; idx < T; idx += 256) {
        const int d = (int)((ent[idx].x >> 17) & 255u);
        const int r = atomicAdd(&cur[d], 1);
        perm[r] = (unsigned short)idx;
    }
    __syncthreads();
    for (int k = t; k < T; k += 256)
        edata[base + k] = ent[perm[k]];          // coalesced global write
}

// ---------------- register-tiled dual GEMM: [XL|XR] = X @ [Wl|Wr] + [bl|br] ----------------
// Outputs packed bf16 (2 per uint): row stride 32 uints.

template <int K>
__global__ __launch_bounds__(256) void k_gemm(const float* __restrict__ X,
                                              const float* __restrict__ Wl,
                                              const float* __restrict__ bl,
                                              const float* __restrict__ Wr,
                                              const float* __restrict__ br,
                                              unsigned* __restrict__ XLh,
                                              unsigned* __restrict__ XRh) {
    constexpr int KC = 32;
    __shared__ float sX[KC][132];
    __shared__ float sW[KC][128];
    const int t = threadIdx.x;
    const int tc = t & 15, tr = t >> 4;
    const int r0 = blockIdx.x * 128;

    float acc[8][8] = {};

    for (int kc = 0; kc < K; kc += KC) {
#pragma unroll
        for (int i = 0; i < 4; ++i) {
            int l = t + 256 * i;
            int row = l >> 3;
            int kq = (l & 7) * 4;
            int rr = min(r0 + row, NNODES - 1);
            const float4 v = *(const float4*)&X[(size_t)rr * K + kc + kq];
            sX[kq + 0][row] = v.x;
            sX[kq + 1][row] = v.y;
            sX[kq + 2][row] = v.z;
            sX[kq + 3][row] = v.w;
        }
#pragma unroll
        for (int i = 0; i < 4; ++i) {
            int l = t + 256 * i;
            int k = l >> 5;
            int cq = l & 31;
            const float* sp = (cq < 16) ? &Wl[(size_t)(kc + k) * 64 + cq * 4]
                                        : &Wr[(size_t)(kc + k) * 64 + (cq - 16) * 4];
            *(float4*)&sW[k][cq * 4] = *(const float4*)sp;
        }
        __syncthreads();
#pragma unroll 4
        for (int k = 0; k < KC; ++k) {
            float xf[8], wf[8];
            *(float4*)&xf[0] = *(const float4*)&sX[k][tr * 8];
            *(float4*)&xf[4] = *(const float4*)&sX[k][tr * 8 + 4];
            *(float4*)&wf[0] = *(const float4*)&sW[k][tc * 8];
            *(float4*)&wf[4] = *(const float4*)&sW[k][tc * 8 + 4];
#pragma unroll
            for (int i2 = 0; i2 < 8; ++i2)
#pragma unroll
                for (int j = 0; j < 8; ++j)
                    acc[i2][j] += xf[i2] * wf[j];
        }
        __syncthreads();
    }

    const bool isL = (tc < 8);
    const int cb = isL ? tc * 8 : tc * 8 - 64;
    const float* bb = isL ? bl : br;
    unsigned* OUT = isL ? XLh : XRh;
    float4 b0 = *(const float4*)&bb[cb];
    float4 b1 = *(const float4*)&bb[cb + 4];
#pragma unroll
    for (int i = 0; i < 8; ++i) {
        int row = r0 + tr * 8 + i;
        if (row < NNODES) {
            uint4 v;
            v.x = pack_bf2(acc[i][0] + b0.x, acc[i][1] + b0.y);
            v.y = pack_bf2(acc[i][2] + b0.z, acc[i][3] + b0.w);
            v.z = pack_bf2(acc[i][4] + b1.x, acc[i][5] + b1.y);
            v.w = pack_bf2(acc[i][6] + b1.z, acc[i][7] + b1.w);
            *(uint4*)&OUT[(size_t)row * 32 + (cb >> 1)] = v;
        }
    }
}

// ---------------- fused GATv2 edge pass ----------------
// One wave per node. lane = 8*group + fl; group g handles edge e+g; lane holds
// features [fl*8, fl*8+8) from one uint4 of packed bf16. 2-deep software
// pipeline (metas 2 batches ahead, gathers 1 iter ahead). Fused leaky-relu:
// att*leaky(m) = 0.6*att*m + 0.4*att*|m| (|m| = free VOP3 modifier).
// Per-wave LDS combine, stride-65 scalar stores (conflict-free), no barrier.

__global__ __launch_bounds__(256) void k_edge(const uint4* __restrict__ XLh,
                                              const uint4* __restrict__ XRh,
                                              const int* __restrict__ rowptr,
                                              const uint2* __restrict__ edata,
                                              const float* __restrict__ We,
                                              const float* __restrict__ att,
                                              const float* __restrict__ bias,
                                              const float* __restrict__ easum,
                                              float* __restrict__ H) {
    __shared__ float red[4][8][65];              // stride 65: bank = g+8*fl+k (2/bank)
    const int wave = threadIdx.x >> 6, lane = threadIdx.x & 63;
    const int g = lane >> 3, fl = lane & 7;
    const int fo = fl * 8;
    float We8[8], att8[8];
    *(float4*)&We8[0] = *(const float4*)&We[fo];
    *(float4*)&We8[4] = *(const float4*)&We[fo + 4];
    *(float4*)&att8[0] = *(const float4*)&att[fo];
    *(float4*)&att8[4] = *(const float4*)&att[fo + 4];
    const float bias_l = bias[lane];
    const float ea_mean = easum[0] * (1.0f / NEDGES);

    const int i = blockIdx.x * 4 + wave;         // exact grid: always < NNODES

    float xr8[8], xl8[8], acc8[8];
    unpack_bf8(XRh[(size_t)i * 8 + fl], xr8);
    unpack_bf8(XLh[(size_t)i * 8 + fl], xl8);

    // self-loop (src=i, ea=ea_mean): wave-uniform logit
    float d1 = 0.f, d2 = 0.f;
#pragma unroll
    for (int f = 0; f < 8; ++f) {
        const float m = fmaf(ea_mean, We8[f], xr8[f]) + xl8[f];
        d1 = fmaf(att8[f], m, d1);
        d2 = fmaf(att8[f], fabsf(m), d2);
    }
    float pt = 0.6f * d1 + 0.4f * d2;
    pt += __shfl_xor(pt, 1);
    pt += __shfl_xor(pt, 2);
    pt += __shfl_xor(pt, 4);
    float M = pt;
    float S = (g == 0) ? 1.f : 0.f;              // per-group partial denominator
#pragma unroll
    for (int f = 0; f < 8; ++f) acc8[f] = (g == 0) ? xl8[f] : 0.f;

    const int e0 = rowptr[i];
    const int ne = rowptr[i + 1] - e0;
    const uint2 z2 = make_uint2(0u, 0u);

    // prologue: metas for batches 0-3, gathers for batches 0-1
    uint2 seA = (g < ne) ? edata[e0 + g] : z2;
    uint2 seB = (8 + g < ne) ? edata[e0 + 8 + g] : z2;
    uint4 wA = XLh[(size_t)(seA.x & 0x1FFFFu) * 8 + fl];
    uint4 wB = XLh[(size_t)(seB.x & 0x1FFFFu) * 8 + fl];
    uint2 seC = (16 + g < ne) ? edata[e0 + 16 + g] : z2;
    uint2 seD = (24 + g < ne) ? edata[e0 + 24 + g] : z2;

    for (int e = 0; e < ne; e += 16) {
        // issue next-iter gathers (metas ready) + metas 2 iters ahead
        const uint4 wC = XLh[(size_t)(seC.x & 0x1FFFFu) * 8 + fl];
        const uint4 wD = XLh[(size_t)(seD.x & 0x1FFFFu) * 8 + fl];
        const uint2 seE = (e + 32 + g < ne) ? edata[e0 + e + 32 + g] : z2;
        const uint2 seF = (e + 40 + g < ne) ? edata[e0 + e + 40 + g] : z2;

        // ---- batch A (edges e..e+7) ----
        {
            const bool valid = (e + g) < ne;
            const float eav = __uint_as_float(seA.y);
            float v8[8];
            unpack_bf8(wA, v8);
            float s1 = 0.f, s2 = 0.f;
#pragma unroll
            for (int f = 0; f < 8; ++f) {
                const float m = fmaf(eav, We8[f], xr8[f]) + v8[f];
                s1 = fmaf(att8[f], m, s1);
                s2 = fmaf(att8[f], fabsf(m), s2);
            }
            float d = 0.6f * s1 + 0.4f * s2;
            d += __shfl_xor(d, 1);
            d += __shfl_xor(d, 2);
            d += __shfl_xor(d, 4);
            const float a = valid ? d : -1e30f;
            if (__any(a > M)) {
                float am = fmaxf(a, __shfl_xor(a, 8));
                am = fmaxf(am, __shfl_xor(am, 16));
                am = fmaxf(am, __shfl_xor(am, 32));
                const float sc = __expf(M - am);
                S *= sc;
#pragma unroll
                for (int f = 0; f < 8; ++f) acc8[f] *= sc;
                M = am;
            }
            const float p = __expf(a - M);
            S += p;
#pragma unroll
            for (int f = 0; f < 8; ++f) acc8[f] = fmaf(p, v8[f], acc8[f]);
        }
        // ---- batch B (edges e+8..e+15) ----
        {
            const bool valid = (e + 8 + g) < ne;
            const float eav = __uint_as_float(seB.y);
            float v8[8];
            unpack_bf8(wB, v8);
            float s1 = 0.f, s2 = 0.f;
#pragma unroll
            for (int f = 0; f < 8; ++f) {
                const float m = fmaf(eav, We8[f], xr8[f]) + v8[f];
                s1 = fmaf(att8[f], m, s1);
                s2 = fmaf(att8[f], fabsf(m), s2);
            }
            float d = 0.6f * s1 + 0.4f * s2;
            d += __shfl_xor(d, 1);
            d += __shfl_xor(d, 2);
            d += __shfl_xor(d, 4);
            const float a = valid ? d : -1e30f;
            if (__any(a > M)) {
                float am = fmaxf(a, __shfl_xor(a, 8));
                am = fmaxf(am, __shfl_xor(am, 16));
                am = fmaxf(am, __shfl_xor(am, 32));
                const float sc = __expf(M - am);
                S *= sc;
#pragma unroll
                for (int f = 0; f < 8; ++f) acc8[f] *= sc;
                M = am;
            }
            const float p = __expf(a - M);
            S += p;
#pragma unroll
            for (int f = 0; f < 8; ++f) acc8[f] = fmaf(p, v8[f], acc8[f]);
        }

        seA = seC; seB = seD; seC = seE; seD = seF;
        wA = wC; wB = wD;
    }

    // reduce S across groups (xor 8/16/32 touches g bits only)
    S += __shfl_xor(S, 8);
    S += __shfl_xor(S, 16);
    S += __shfl_xor(S, 32);

    // per-wave LDS transpose-combine (no inter-wave sharing -> no barrier)
#pragma unroll
    for (int k = 0; k < 8; ++k) red[wave][g][fo + k] = acc8[k];
    asm volatile("" ::: "memory");
    __builtin_amdgcn_wave_barrier();             // fence: DS ops in-order within wave
    float o = 0.f;
#pragma unroll
    for (int gg = 0; gg < 8; ++gg) o += red[wave][gg][lane];
    o = fmaxf(o / S + bias_l, 0.f);              // bias + fused ReLU
    H[(size_t)i * 64 + lane] = o;                // 64-lane coalesced store
}

// ---------------- tail: mean pool + linear + softmax ----------------

__global__ __launch_bounds__(256) void k_colsum(const float* __restrict__ H,
                                                float* __restrict__ gsum) {
    int wave = threadIdx.x >> 6, lane = threadIdx.x & 63;
    float s = 0.f;
    for (int r = blockIdx.x * 4 + wave; r < NNODES; r += gridDim.x * 4)
        s += H[(size_t)r * 64 + lane];
    __shared__ float ls[4][64];
    ls[wave][lane] = s;
    __syncthreads();
    if (wave == 0) {
        s = ls[0][lane] + ls[1][lane] + ls[2][lane] + ls[3][lane];
        atomicAdd(&gsum[lane], s);
    }
}

__global__ __launch_bounds__(64) void k_head(const float* __restrict__ gsum,
                                             const float* __restrict__ Wlin,
                                             const float* __restrict__ blin,
                                             float* __restrict__ out) {
    int lane = threadIdx.x;
    float g = gsum[lane] * (1.0f / NNODES);
    float a0 = wave_sum64(g * Wlin[lane * 2 + 0]);
    float a1 = wave_sum64(g * Wlin[lane * 2 + 1]);
    if (lane == 0) {
        float l0 = a0 + blin[0], l1 = a1 + blin[1];
        float mx = fmaxf(l0, l1);
        float e0 = __expf(l0 - mx), e1 = __expf(l1 - mx);
        float inv = 1.f / (e0 + e1);
        out[0] = e0 * inv;
        out[1] = e1 * inv;
    }
}

extern "C" void kernel_launch(void* const* d_in, const int* in_sizes, int n_in,
                              void* d_out, int out_size, void* d_ws, size_t ws_size,
                              hipStream_t stream) {
    const float* x = (const float*)d_in[0];
    const int* ei = (const int*)d_in[1];
    const float* ea = (const float*)d_in[2];
    const int* src = ei;
    const int* dst = ei + NEDGES;
    auto W = [&](int i) { return (const float*)d_in[i]; };

    char* ws = (char*)d_ws;
    size_t off = 0;
    auto alloc = [&](size_t bytes) {
        void* p = ws + off;
        off += (bytes + 255) & ~(size_t)255;
        return p;
    };
    unsigned* XLh = (unsigned*)alloc((size_t)NNODES * 64 * 2);   // packed bf16
    unsigned* XRh = (unsigned*)alloc((size_t)NNODES * 64 * 2);   // packed bf16
    float* Hb = (float*)alloc((size_t)NNODES * 64 * 4);
    int* rowptr = (int*)alloc((size_t)(NNODES + 1) * 4);
    uint2* edata = (uint2*)alloc((size_t)NEDGES * 8);
    float* easum = (float*)alloc(4);
    float* gsum = (float*)alloc(64 * 4);
    int* gcnt = (int*)alloc((size_t)FLATN * 4);
    int* lscan = (int*)alloc((size_t)FLATN * 4);
    int* goff = (int*)alloc((size_t)FLATN * 4);
    int* part2 = (int*)alloc((size_t)SCB * 4);
    int* boff2 = (int*)alloc((size_t)SCB * 4);
    uint2* tmps = (uint2*)Hb;  // 12.8 MB <= Hb's 25.6 MB; Hb dead until layer-1 k_edge

    hipMemsetAsync(easum, 0, 4, stream);
    hipMemsetAsync(gsum, 0, 64 * 4, stream);

    k_lsort<<<NBLK, 256, 0, stream>>>(src, dst, ea, tmps, gcnt, lscan, easum);
    k_part2<<<SCB, 256, 0, stream>>>(gcnt, FLATN, part2);
    k_scanb2<<<1, 1024, 0, stream>>>(part2, SCB, boff2, rowptr);
    k_scanfin2<<<SCB, 256, 0, stream>>>(gcnt, FLATN, boff2, goff);
    k_fsort<<<NB, 256, 0, stream>>>(tmps, lscan, goff, rowptr, edata);

    int gemm_grid = (NNODES + 127) / 128;
    int edge_grid = NNODES / 4;   // exact: one wave per node

    k_gemm<128><<<gemm_grid, 256, 0, stream>>>(x, W(3), W(4), W(5), W(6), XLh, XRh);
    k_edge<<<edge_grid, 256, 0, stream>>>((const uint4*)XLh, (const uint4*)XRh, rowptr, edata,
                                          W(7), W(8), W(9), easum, Hb);
    k_gemm<64><<<gemm_grid, 256, 0, stream>>>(Hb, W(10), W(11), W(12), W(13), XLh, XRh);
    k_edge<<<edge_grid, 256, 0, stream>>>((const uint4*)XLh, (const uint4*)XRh, rowptr, edata,
                                          W(14), W(15), W(16), easum, Hb);
    k_gemm<64><<<gemm_grid, 256, 0, stream>>>(Hb, W(17), W(18), W(19), W(20), XLh, XRh);
    k_edge<<<edge_grid, 256, 0, stream>>>((const uint4*)XLh, (const uint4*)XRh, rowptr, edata,
                                          W(21), W(22), W(23), easum, Hb);

    k_colsum<<<1024, 256, 0, stream>>>(Hb, gsum);
    k_head<<<1, 64, 0, stream>>>(gsum, W(24), W(25), (float*)d_out);
}

// Round 10
// 414.424 us; speedup vs baseline: 1.1647x; 1.1647x over previous
//
#include <hip/hip_runtime.h>
#include <hip/hip_bf16.h>

#define NNODES 100000
#define NEDGES 1600000
#define NEG_SLOPE 0.2f

#define CHUNK 4096
#define EPT 16                                  // edges per thread in k_lsort
#define NBLK ((NEDGES + CHUNK - 1) / CHUNK)     // 391 sort blocks
#define NB ((NNODES + 255) / 256)               // 391 buckets (256 nodes each)
#define FLATN (NB * NBLK)                       // 152881
#define SCB ((FLATN + 255) / 256)               // 598
#define FCAP 5632                               // bucket entry cap (mean 4092, +24 sigma)

__device__ __forceinline__ float wave_sum64(float v) {
#pragma unroll
    for (int off = 1; off < 64; off <<= 1) v += __shfl_xor(v, off, 64);
    return v;
}

__device__ __forceinline__ int wave_sum64i(int v) {
#pragma unroll
    for (int off = 1; off < 64; off <<= 1) v += __shfl_xor(v, off, 64);
    return v;
}

// pack two f32 -> one uint of 2 bf16 (RNE)
__device__ __forceinline__ unsigned pack_bf2(float a, float b) {
    unsigned ua = __float_as_uint(a), ub = __float_as_uint(b);
    ua = (ua + 0x7FFFu + ((ua >> 16) & 1u)) >> 16;
    ub = (ub + 0x7FFFu + ((ub >> 16) & 1u));
    return ua | (ub & 0xFFFF0000u);
}

__device__ __forceinline__ void unpack_bf8(uint4 w, float* f) {
    f[0] = __uint_as_float(w.x << 16);
    f[1] = __uint_as_float(w.x & 0xFFFF0000u);
    f[2] = __uint_as_float(w.y << 16);
    f[3] = __uint_as_float(w.y & 0xFFFF0000u);
    f[4] = __uint_as_float(w.z << 16);
    f[5] = __uint_as_float(w.z & 0xFFFF0000u);
    f[6] = __uint_as_float(w.w << 16);
    f[7] = __uint_as_float(w.w & 0xFFFF0000u);
}

// ---------------- phase A: per-chunk counting sort by bucket (all-coalesced) ----------------

__global__ __launch_bounds__(256) void k_lsort(const int* __restrict__ src,
                                               const int* __restrict__ dst,
                                               const float* __restrict__ ea,
                                               uint2* __restrict__ tmps,
                                               int* __restrict__ gcnt,
                                               int* __restrict__ lscan,
                                               float* __restrict__ easum) {
    __shared__ uint2 ent[CHUNK];                 // 32 KB
    __shared__ unsigned short perm[CHUNK];       // 8 KB
    __shared__ int hist[NB];
    __shared__ int cur[NB];
    __shared__ float ws[4];
    const int t = threadIdx.x;
    const int j = blockIdx.x;
    const int base = j * CHUNK;
    const int n = min(CHUNK, NEDGES - base);

    for (int b = t; b < NB; b += 256) hist[b] = 0;
    __syncthreads();

    int bkt[EPT];
    float s = 0.f;
#pragma unroll
    for (int k = 0; k < EPT; ++k) {
        const int l = t + k * 256;
        bkt[k] = -1;
        if (l < n) {
            const int i = base + l;
            const int d = dst[i];
            const float e = ea[i];
            const int b = d >> 8;
            bkt[k] = b;
            ent[l] = make_uint2((unsigned)src[i] | ((unsigned)(d & 255) << 17),
                                __float_as_uint(e));
            atomicAdd(&hist[b], 1);
            s += e;
        }
    }
    s = wave_sum64(s);
    if ((t & 63) == 0) ws[t >> 6] = s;
    __syncthreads();
    if (t == 0) atomicAdd(easum, ws[0] + ws[1] + ws[2] + ws[3]);

    // exclusive scan of hist[0..NB) -> cur, wave 0 only (56 lanes x 7 elems)
    if (t < 64) {
        int x[7];
        int run = 0;
#pragma unroll
        for (int q = 0; q < 7; ++q) {
            const int idx = t * 7 + q;
            x[q] = (idx < NB) ? hist[idx] : 0;
            run += x[q];
        }
        int inc = run;
#pragma unroll
        for (int o = 1; o < 64; o <<= 1) {
            int u = __shfl_up(inc, o, 64);
            if (t >= o) inc += u;
        }
        int r = inc - run;   // lane-exclusive
#pragma unroll
        for (int q = 0; q < 7; ++q) {
            const int idx = t * 7 + q;
            if (idx < NB) cur[idx] = r;
            r += x[q];
        }
    }
    __syncthreads();

#pragma unroll
    for (int k = 0; k < EPT; ++k) {
        if (bkt[k] >= 0) {
            const int r = atomicAdd(&cur[bkt[k]], 1);
            perm[r] = (unsigned short)(t + k * 256);
        }
    }
    __syncthreads();

    for (int o = t; o < n; o += 256)
        tmps[base + o] = ent[perm[o]];           // coalesced global write
    for (int b = t; b < NB; b += 256) {
        gcnt[b * NBLK + j] = hist[b];            // bucket-major (for flat scan)
        lscan[j * NB + b] = cur[b] - hist[b];    // local exclusive offset
    }
}

// ---------------- flat exclusive scan of gcnt[FLATN] -> goff ----------------

__global__ __launch_bounds__(256) void k_part2(const int* __restrict__ v, int n,
                                               int* __restrict__ bsum) {
    int i = blockIdx.x * 256 + threadIdx.x;
    int x = (i < n) ? v[i] : 0;
    x = wave_sum64i(x);
    __shared__ int wsh[4];
    if ((threadIdx.x & 63) == 0) wsh[threadIdx.x >> 6] = x;
    __syncthreads();
    if (threadIdx.x == 0) bsum[blockIdx.x] = wsh[0] + wsh[1] + wsh[2] + wsh[3];
}

__global__ __launch_bounds__(1024) void k_scanb2(const int* __restrict__ bsum, int nb,
                                                 int* __restrict__ boff,
                                                 int* __restrict__ rowptr) {
    __shared__ int sh[1024];
    int t = threadIdx.x;
    int v = (t < nb) ? bsum[t] : 0;
    sh[t] = v;
    __syncthreads();
    for (int off = 1; off < 1024; off <<= 1) {
        int u = (t >= off) ? sh[t - off] : 0;
        __syncthreads();
        sh[t] += u;
        __syncthreads();
    }
    if (t < nb) boff[t] = sh[t] - v;
    if (t == 0) rowptr[NNODES] = NEDGES;
}

__global__ __launch_bounds__(256) void k_scanfin2(const int* __restrict__ v, int n,
                                                  const int* __restrict__ boff,
                                                  int* __restrict__ out) {
    int t = threadIdx.x, lane = t & 63, wave = t >> 6;
    int i = blockIdx.x * 256 + t;
    int x = (i < n) ? v[i] : 0;
    int orig = x;
#pragma unroll
    for (int off = 1; off < 64; off <<= 1) {
        int u = __shfl_up(x, off, 64);
        if (lane >= off) x += u;
    }
    __shared__ int wsh[4];
    if (lane == 63) wsh[wave] = x;
    __syncthreads();
    int wexc = 0;
    for (int w = 0; w < wave; ++w) wexc += wsh[w];
    if (i < n) out[i] = boff[blockIdx.x] + wexc + x - orig;
}

// ---------------- phase C: per-bucket gather + LDS counting sort by node ----------------

__global__ __launch_bounds__(256) void k_fsort(const uint2* __restrict__ tmps,
                                               const int* __restrict__ lscan,
                                               const int* __restrict__ goff,
                                               int* __restrict__ rowptr,
                                               uint2* __restrict__ edata) {
    __shared__ uint2 ent[FCAP];                  // 44 KB
    __shared__ unsigned short perm[FCAP];        // 11 KB
    __shared__ int joff[NBLK + 1];
    __shared__ int jsrc[NBLK];
    __shared__ int hist[256];
    __shared__ int cur[256];
    const int b = blockIdx.x;
    const int t = threadIdx.x;
    const int base = goff[b * NBLK];             // bucket base position in edata

    for (int q = t; q < 256; q += 256) hist[q] = 0;
    for (int j = t; j < NBLK; j += 256) {
        joff[j] = goff[b * NBLK + j] - base;
        jsrc[j] = j * CHUNK + lscan[j * NB + b];
    }
    if (t == 0) joff[NBLK] = ((b == NB - 1) ? NEDGES : goff[(b + 1) * NBLK]) - base;
    __syncthreads();
    const int T = min(joff[NBLK], FCAP);

    for (int idx = t; idx < T; idx += 256) {
        int lo = 0, hi = NBLK;
        while (hi - lo > 1) { int mid = (lo + hi) >> 1; if (joff[mid] <= idx) lo = mid; else hi = mid; }
        const uint2 e = tmps[jsrc[lo] + (idx - joff[lo])];   // piecewise-coalesced
        ent[idx] = e;
        atomicAdd(&hist[(e.x >> 17) & 255u], 1);
    }
    __syncthreads();

    // exclusive scan hist[0..256) -> cur, wave 0 (64 lanes x 4)
    if (t < 64) {
        int x[4];
        int run = 0;
#pragma unroll
        for (int q = 0; q < 4; ++q) { x[q] = hist[t * 4 + q]; run += x[q]; }
        int inc = run;
#pragma unroll
        for (int o = 1; o < 64; o <<= 1) {
            int u = __shfl_up(inc, o, 64);
            if (t >= o) inc += u;
        }
        int r = inc - run;
#pragma unroll
        for (int q = 0; q < 4; ++q) { cur[t * 4 + q] = r; r += x[q]; }
    }
    __syncthreads();

    {
        const int i = b * 256 + t;
        if (i < NNODES) rowptr[i] = base + cur[t];
    }
    __syncthreads();    // rowptr reads of cur must complete before rank mutation

    for (int idx = t; idx < T; idx += 256) {
        const int d = (int)((ent[idx].x >> 17) & 255u);
        const int r = atomicAdd(&cur[d], 1);
        perm[r] = (unsigned short)idx;
    }
    __syncthreads();
    for (int k = t; k < T; k += 256)
        edata[base + k] = ent[perm[k]];          // coalesced global write
}

// ---------------- register-tiled dual GEMM: [XL|XR] = X @ [Wl|Wr] + [bl|br] ----------------
// Outputs packed bf16 (2 per uint): row stride 32 uints.

template <int K>
__global__ __launch_bounds__(256) void k_gemm(const float* __restrict__ X,
                                              const float* __restrict__ Wl,
                                              const float* __restrict__ bl,
                                              const float* __restrict__ Wr,
                                              const float* __restrict__ br,
                                              unsigned* __restrict__ XLh,
                                              unsigned* __restrict__ XRh) {
    constexpr int KC = 32;
    __shared__ float sX[KC][132];
    __shared__ float sW[KC][128];
    const int t = threadIdx.x;
    const int tc = t & 15, tr = t >> 4;
    const int r0 = blockIdx.x * 128;

    float acc[8][8] = {};

    for (int kc = 0; kc < K; kc += KC) {
#pragma unroll
        for (int i = 0; i < 4; ++i) {
            int l = t + 256 * i;
            int row = l >> 3;
            int kq = (l & 7) * 4;
            int rr = min(r0 + row, NNODES - 1);
            const float4 v = *(const float4*)&X[(size_t)rr * K + kc + kq];
            sX[kq + 0][row] = v.x;
            sX[kq + 1][row] = v.y;
            sX[kq + 2][row] = v.z;
            sX[kq + 3][row] = v.w;
        }
#pragma unroll
        for (int i = 0; i < 4; ++i) {
            int l = t + 256 * i;
            int k = l >> 5;
            int cq = l & 31;
            const float* sp = (cq < 16) ? &Wl[(size_t)(kc + k) * 64 + cq * 4]
                                        : &Wr[(size_t)(kc + k) * 64 + (cq - 16) * 4];
            *(float4*)&sW[k][cq * 4] = *(const float4*)sp;
        }
        __syncthreads();
#pragma unroll 4
        for (int k = 0; k < KC; ++k) {
            float xf[8], wf[8];
            *(float4*)&xf[0] = *(const float4*)&sX[k][tr * 8];
            *(float4*)&xf[4] = *(const float4*)&sX[k][tr * 8 + 4];
            *(float4*)&wf[0] = *(const float4*)&sW[k][tc * 8];
            *(float4*)&wf[4] = *(const float4*)&sW[k][tc * 8 + 4];
#pragma unroll
            for (int i2 = 0; i2 < 8; ++i2)
#pragma unroll
                for (int j = 0; j < 8; ++j)
                    acc[i2][j] += xf[i2] * wf[j];
        }
        __syncthreads();
    }

    const bool isL = (tc < 8);
    const int cb = isL ? tc * 8 : tc * 8 - 64;
    const float* bb = isL ? bl : br;
    unsigned* OUT = isL ? XLh : XRh;
    float4 b0 = *(const float4*)&bb[cb];
    float4 b1 = *(const float4*)&bb[cb + 4];
#pragma unroll
    for (int i = 0; i < 8; ++i) {
        int row = r0 + tr * 8 + i;
        if (row < NNODES) {
            uint4 v;
            v.x = pack_bf2(acc[i][0] + b0.x, acc[i][1] + b0.y);
            v.y = pack_bf2(acc[i][2] + b0.z, acc[i][3] + b0.w);
            v.z = pack_bf2(acc[i][4] + b1.x, acc[i][5] + b1.y);
            v.w = pack_bf2(acc[i][6] + b1.z, acc[i][7] + b1.w);
            *(uint4*)&OUT[(size_t)row * 32 + (cb >> 1)] = v;
        }
    }
}

// ---------------- fused GATv2 edge pass ----------------
// One wave per node. lane = 8*group + fl; group g handles edge e+g (8/batch);
// lane holds features [fl*8, fl*8+8) from one uint4 of packed bf16.
// R7 memory structure (meta prefetch 1 batch ahead, gather at use) +
// fused leaky: att*leaky(m) = 0.6*(att.m) + 0.4*(att.|m|), |m| free modifier.
// Per-wave LDS combine, stride-65 scalar stores, no block barrier.

__global__ __launch_bounds__(256) void k_edge(const uint4* __restrict__ XLh,
                                              const uint4* __restrict__ XRh,
                                              const int* __restrict__ rowptr,
                                              const uint2* __restrict__ edata,
                                              const float* __restrict__ We,
                                              const float* __restrict__ att,
                                              const float* __restrict__ bias,
                                              const float* __restrict__ easum,
                                              float* __restrict__ H) {
    __shared__ float red[4][8][65];              // bank = (g + 8*fl + k) % 32: 2/bank (free)
    const int wave = threadIdx.x >> 6, lane = threadIdx.x & 63;
    const int g = lane >> 3, fl = lane & 7;
    const int fo = fl * 8;
    float We8[8], att8[8];
    *(float4*)&We8[0] = *(const float4*)&We[fo];
    *(float4*)&We8[4] = *(const float4*)&We[fo + 4];
    *(float4*)&att8[0] = *(const float4*)&att[fo];
    *(float4*)&att8[4] = *(const float4*)&att[fo + 4];
    const float bias_l = bias[lane];
    const float ea_mean = easum[0] * (1.0f / NEDGES);

    const int i = blockIdx.x * 4 + wave;         // exact grid: always < NNODES

    float xr8[8], xl8[8], acc8[8];
    unpack_bf8(XRh[(size_t)i * 8 + fl], xr8);
    unpack_bf8(XLh[(size_t)i * 8 + fl], xl8);

    // self-loop (src=i, ea=ea_mean): wave-uniform logit
    {
        float s1 = 0.f, s2 = 0.f;
#pragma unroll
        for (int f = 0; f < 8; ++f) {
            const float m = fmaf(ea_mean, We8[f], xr8[f]) + xl8[f];
            s1 = fmaf(att8[f], m, s1);
            s2 = fmaf(att8[f], fabsf(m), s2);
        }
        float pt = fmaf(0.6f, s1, 0.4f * s2);
        pt += __shfl_xor(pt, 1);
        pt += __shfl_xor(pt, 2);
        pt += __shfl_xor(pt, 4);
        xl8[0] = xl8[0];                         // keep xl8 live for init below
        acc8[0] = 0.f;                           // placeholder (overwritten below)
        // store logit in s1 slot via broadcast
        // (fallthrough: M set after block)
        red[wave][0][64] = pt;                   // unused slot, avoids recompute
    }
    float M = red[wave][0][64];
    __builtin_amdgcn_wave_barrier();
    float S = (g == 0) ? 1.f : 0.f;              // per-group partial denominator
#pragma unroll
    for (int f = 0; f < 8; ++f) acc8[f] = (g == 0) ? xl8[f] : 0.f;

    const int e0 = rowptr[i];
    const int ne = rowptr[i + 1] - e0;
    const uint2 z2 = make_uint2(0u, 0u);

    uint2 se = (g < ne) ? edata[e0 + g] : z2;    // meta prefetch, 1 batch ahead
    for (int e = 0; e < ne; e += 8) {
        const uint2 se_cur = se;
        const bool valid = (e + g) < ne;
        if (e + 8 + g < ne) se = edata[e0 + e + 8 + g];
        const int s = (int)(se_cur.x & 0x1FFFFu);
        const float eav = __uint_as_float(se_cur.y);
        float v8[8];
        unpack_bf8(XLh[(size_t)s * 8 + fl], v8);

        float s1 = 0.f, s2 = 0.f;
#pragma unroll
        for (int f = 0; f < 8; ++f) {
            const float m = fmaf(eav, We8[f], xr8[f]) + v8[f];
            s1 = fmaf(att8[f], m, s1);
            s2 = fmaf(att8[f], fabsf(m), s2);
        }
        float d = fmaf(0.6f, s1, 0.4f * s2);
        d += __shfl_xor(d, 1);
        d += __shfl_xor(d, 2);
        d += __shfl_xor(d, 4);                   // group-uniform logit
        const float a = valid ? d : -1e30f;

        if (__any(a > M)) {                      // ballot; wave-uniform branch
            float am = fmaxf(a, __shfl_xor(a, 8));
            am = fmaxf(am, __shfl_xor(am, 16));
            am = fmaxf(am, __shfl_xor(am, 32));
            const float sc = __expf(M - am);     // exact rescale
            S *= sc;
#pragma unroll
            for (int f = 0; f < 8; ++f) acc8[f] *= sc;
            M = am;
        }
        const float p = __expf(a - M);           // 0 for invalid groups
        S += p;                                  // group-partial (deferred reduce)
#pragma unroll
        for (int f = 0; f < 8; ++f) acc8[f] = fmaf(p, v8[f], acc8[f]);
    }

    // reduce S across groups (xor 8/16/32 touches g bits only)
    S += __shfl_xor(S, 8);
    S += __shfl_xor(S, 16);
    S += __shfl_xor(S, 32);

    // per-wave LDS transpose-combine (no inter-wave sharing -> no block barrier)
#pragma unroll
    for (int k = 0; k < 8; ++k) red[wave][g][fo + k] = acc8[k];
    asm volatile("" ::: "memory");
    __builtin_amdgcn_wave_barrier();             // DS ops complete in-order per wave
    float o = 0.f;
#pragma unroll
    for (int gg = 0; gg < 8; ++gg) o += red[wave][gg][lane];
    o = fmaxf(o / S + bias_l, 0.f);              // bias + fused ReLU
    H[(size_t)i * 64 + lane] = o;                // 64-lane coalesced store
}

// ---------------- tail: mean pool + linear + softmax ----------------

__global__ __launch_bounds__(256) void k_colsum(const float* __restrict__ H,
                                                float* __restrict__ gsum) {
    int wave = threadIdx.x >> 6, lane = threadIdx.x & 63;
    float s = 0.f;
    for (int r = blockIdx.x * 4 + wave; r < NNODES; r += gridDim.x * 4)
        s += H[(size_t)r * 64 + lane];
    __shared__ float ls[4][64];
    ls[wave][lane] = s;
    __syncthreads();
    if (wave == 0) {
        s = ls[0][lane] + ls[1][lane] + ls[2][lane] + ls[3][lane];
        atomicAdd(&gsum[lane], s);
    }
}

__global__ __launch_bounds__(64) void k_head(const float* __restrict__ gsum,
                                             const float* __restrict__ Wlin,
                                             const float* __restrict__ blin,
                                             float* __restrict__ out) {
    int lane = threadIdx.x;
    float g = gsum[lane] * (1.0f / NNODES);
    float a0 = wave_sum64(g * Wlin[lane * 2 + 0]);
    float a1 = wave_sum64(g * Wlin[lane * 2 + 1]);
    if (lane == 0) {
        float l0 = a0 + blin[0], l1 = a1 + blin[1];
        float mx = fmaxf(l0, l1);
        float e0 = __expf(l0 - mx), e1 = __expf(l1 - mx);
        float inv = 1.f / (e0 + e1);
        out[0] = e0 * inv;
        out[1] = e1 * inv;
    }
}

extern "C" void kernel_launch(void* const* d_in, const int* in_sizes, int n_in,
                              void* d_out, int out_size, void* d_ws, size_t ws_size,
                              hipStream_t stream) {
    const float* x = (const float*)d_in[0];
    const int* ei = (const int*)d_in[1];
    const float* ea = (const float*)d_in[2];
    const int* src = ei;
    const int* dst = ei + NEDGES;
    auto W = [&](int i) { return (const float*)d_in[i]; };

    char* ws = (char*)d_ws;
    size_t off = 0;
    auto alloc = [&](size_t bytes) {
        void* p = ws + off;
        off += (bytes + 255) & ~(size_t)255;
        return p;
    };
    unsigned* XLh = (unsigned*)alloc((size_t)NNODES * 64 * 2);   // packed bf16
    unsigned* XRh = (unsigned*)alloc((size_t)NNODES * 64 * 2);   // packed bf16
    float* Hb = (float*)alloc((size_t)NNODES * 64 * 4);
    int* rowptr = (int*)alloc((size_t)(NNODES + 1) * 4);
    uint2* edata = (uint2*)alloc((size_t)NEDGES * 8);
    float* easum = (float*)alloc(4);
    float* gsum = (float*)alloc(64 * 4);
    int* gcnt = (int*)alloc((size_t)FLATN * 4);
    int* lscan = (int*)alloc((size_t)FLATN * 4);
    int* goff = (int*)alloc((size_t)FLATN * 4);
    int* part2 = (int*)alloc((size_t)SCB * 4);
    int* boff2 = (int*)alloc((size_t)SCB * 4);
    uint2* tmps = (uint2*)Hb;  // 12.8 MB <= Hb's 25.6 MB; Hb dead until layer-1 k_edge

    hipMemsetAsync(easum, 0, 4, stream);
    hipMemsetAsync(gsum, 0, 64 * 4, stream);

    k_lsort<<<NBLK, 256, 0, stream>>>(src, dst, ea, tmps, gcnt, lscan, easum);
    k_part2<<<SCB, 256, 0, stream>>>(gcnt, FLATN, part2);
    k_scanb2<<<1, 1024, 0, stream>>>(part2, SCB, boff2, rowptr);
    k_scanfin2<<<SCB, 256, 0, stream>>>(gcnt, FLATN, boff2, goff);
    k_fsort<<<NB, 256, 0, stream>>>(tmps, lscan, goff, rowptr, edata);

    int gemm_grid = (NNODES + 127) / 128;
    int edge_grid = NNODES / 4;   // exact: one wave per node

    k_gemm<128><<<gemm_grid, 256, 0, stream>>>(x, W(3), W(4), W(5), W(6), XLh, XRh);
    k_edge<<<edge_grid, 256, 0, stream>>>((const uint4*)XLh, (const uint4*)XRh, rowptr, edata,
                                          W(7), W(8), W(9), easum, Hb);
    k_gemm<64><<<gemm_grid, 256, 0, stream>>>(Hb, W(10), W(11), W(12), W(13), XLh, XRh);
    k_edge<<<edge_grid, 256, 0, stream>>>((const uint4*)XLh, (const uint4*)XRh, rowptr, edata,
                                          W(14), W(15), W(16), easum, Hb);
    k_gemm<64><<<gemm_grid, 256, 0, stream>>>(Hb, W(17), W(18), W(19), W(20), XLh, XRh);
    k_edge<<<edge_grid, 256, 0, stream>>>((const uint4*)XLh, (const uint4*)XRh, rowptr, edata,
                                          W(21), W(22), W(23), easum, Hb);

    k_colsum<<<1024, 256, 0, stream>>>(Hb, gsum);
    k_head<<<1, 64, 0, stream>>>(gsum, W(24), W(25), (float*)d_out);
}

// Round 11
// 352.675 us; speedup vs baseline: 1.3686x; 1.1751x over previous
//
#include <hip/hip_runtime.h>
#include <hip/hip_bf16.h>

#define NNODES 100000
#define NEDGES 1600000
#define NEG_SLOPE 0.2f

#define CHUNK 4096
#define EPT 16                                  // edges per thread in k_lsort
#define NBLK ((NEDGES + CHUNK - 1) / CHUNK)     // 391 sort blocks
#define NB ((NNODES + 255) / 256)               // 391 buckets (256 nodes each)
#define FLATN (NB * NBLK)                       // 152881
#define SCB ((FLATN + 255) / 256)               // 598
#define FCAP 5632                               // bucket entry cap (mean 4092, +24 sigma)

typedef __attribute__((ext_vector_type(8))) short bf16x8;
typedef __attribute__((ext_vector_type(4))) float f32x4;

__device__ __forceinline__ float wave_sum64(float v) {
#pragma unroll
    for (int off = 1; off < 64; off <<= 1) v += __shfl_xor(v, off, 64);
    return v;
}

__device__ __forceinline__ int wave_sum64i(int v) {
#pragma unroll
    for (int off = 1; off < 64; off <<= 1) v += __shfl_xor(v, off, 64);
    return v;
}

// f32 -> bf16 (RNE)
__device__ __forceinline__ unsigned short bf16rne(float a) {
    unsigned u = __float_as_uint(a);
    return (unsigned short)((u + 0x7FFFu + ((u >> 16) & 1u)) >> 16);
}

// pack two f32 -> one uint of 2 bf16 (RNE); low ushort = a
__device__ __forceinline__ unsigned pack_bf2(float a, float b) {
    unsigned ua = __float_as_uint(a), ub = __float_as_uint(b);
    ua = (ua + 0x7FFFu + ((ua >> 16) & 1u)) >> 16;
    ub = (ub + 0x7FFFu + ((ub >> 16) & 1u));
    return ua | (ub & 0xFFFF0000u);
}

__device__ __forceinline__ void unpack_bf8(uint4 w, float* f) {
    f[0] = __uint_as_float(w.x << 16);
    f[1] = __uint_as_float(w.x & 0xFFFF0000u);
    f[2] = __uint_as_float(w.y << 16);
    f[3] = __uint_as_float(w.y & 0xFFFF0000u);
    f[4] = __uint_as_float(w.z << 16);
    f[5] = __uint_as_float(w.z & 0xFFFF0000u);
    f[6] = __uint_as_float(w.w << 16);
    f[7] = __uint_as_float(w.w & 0xFFFF0000u);
}

// ---------------- phase A: per-chunk counting sort by bucket (all-coalesced) ----------------

__global__ __launch_bounds__(256) void k_lsort(const int* __restrict__ src,
                                               const int* __restrict__ dst,
                                               const float* __restrict__ ea,
                                               uint2* __restrict__ tmps,
                                               int* __restrict__ gcnt,
                                               int* __restrict__ lscan,
                                               float* __restrict__ easum) {
    __shared__ uint2 ent[CHUNK];                 // 32 KB
    __shared__ unsigned short perm[CHUNK];       // 8 KB
    __shared__ int hist[NB];
    __shared__ int cur[NB];
    __shared__ float ws[4];
    const int t = threadIdx.x;
    const int j = blockIdx.x;
    const int base = j * CHUNK;
    const int n = min(CHUNK, NEDGES - base);

    for (int b = t; b < NB; b += 256) hist[b] = 0;
    __syncthreads();

    int bkt[EPT];
    float s = 0.f;
#pragma unroll
    for (int k = 0; k < EPT; ++k) {
        const int l = t + k * 256;
        bkt[k] = -1;
        if (l < n) {
            const int i = base + l;
            const int d = dst[i];
            const float e = ea[i];
            const int b = d >> 8;
            bkt[k] = b;
            ent[l] = make_uint2((unsigned)src[i] | ((unsigned)(d & 255) << 17),
                                __float_as_uint(e));
            atomicAdd(&hist[b], 1);
            s += e;
        }
    }
    s = wave_sum64(s);
    if ((t & 63) == 0) ws[t >> 6] = s;
    __syncthreads();
    if (t == 0) atomicAdd(easum, ws[0] + ws[1] + ws[2] + ws[3]);

    // exclusive scan of hist[0..NB) -> cur, wave 0 only (56 lanes x 7 elems)
    if (t < 64) {
        int x[7];
        int run = 0;
#pragma unroll
        for (int q = 0; q < 7; ++q) {
            const int idx = t * 7 + q;
            x[q] = (idx < NB) ? hist[idx] : 0;
            run += x[q];
        }
        int inc = run;
#pragma unroll
        for (int o = 1; o < 64; o <<= 1) {
            int u = __shfl_up(inc, o, 64);
            if (t >= o) inc += u;
        }
        int r = inc - run;   // lane-exclusive
#pragma unroll
        for (int q = 0; q < 7; ++q) {
            const int idx = t * 7 + q;
            if (idx < NB) cur[idx] = r;
            r += x[q];
        }
    }
    __syncthreads();

#pragma unroll
    for (int k = 0; k < EPT; ++k) {
        if (bkt[k] >= 0) {
            const int r = atomicAdd(&cur[bkt[k]], 1);
            perm[r] = (unsigned short)(t + k * 256);
        }
    }
    __syncthreads();

    for (int o = t; o < n; o += 256)
        tmps[base + o] = ent[perm[o]];           // coalesced global write
    for (int b = t; b < NB; b += 256) {
        gcnt[b * NBLK + j] = hist[b];            // bucket-major (for flat scan)
        lscan[j * NB + b] = cur[b] - hist[b];    // local exclusive offset
    }
}

// ---------------- flat exclusive scan of gcnt[FLATN] -> goff ----------------

__global__ __launch_bounds__(256) void k_part2(const int* __restrict__ v, int n,
                                               int* __restrict__ bsum) {
    int i = blockIdx.x * 256 + threadIdx.x;
    int x = (i < n) ? v[i] : 0;
    x = wave_sum64i(x);
    __shared__ int wsh[4];
    if ((threadIdx.x & 63) == 0) wsh[threadIdx.x >> 6] = x;
    __syncthreads();
    if (threadIdx.x == 0) bsum[blockIdx.x] = wsh[0] + wsh[1] + wsh[2] + wsh[3];
}

__global__ __launch_bounds__(1024) void k_scanb2(const int* __restrict__ bsum, int nb,
                                                 int* __restrict__ boff,
                                                 int* __restrict__ rowptr) {
    __shared__ int sh[1024];
    int t = threadIdx.x;
    int v = (t < nb) ? bsum[t] : 0;
    sh[t] = v;
    __syncthreads();
    for (int off = 1; off < 1024; off <<= 1) {
        int u = (t >= off) ? sh[t - off] : 0;
        __syncthreads();
        sh[t] += u;
        __syncthreads();
    }
    if (t < nb) boff[t] = sh[t] - v;
    if (t == 0) rowptr[NNODES] = NEDGES;
}

__global__ __launch_bounds__(256) void k_scanfin2(const int* __restrict__ v, int n,
                                                  const int* __restrict__ boff,
                                                  int* __restrict__ out) {
    int t = threadIdx.x, lane = t & 63, wave = t >> 6;
    int i = blockIdx.x * 256 + t;
    int x = (i < n) ? v[i] : 0;
    int orig = x;
#pragma unroll
    for (int off = 1; off < 64; off <<= 1) {
        int u = __shfl_up(x, off, 64);
        if (lane >= off) x += u;
    }
    __shared__ int wsh[4];
    if (lane == 63) wsh[wave] = x;
    __syncthreads();
    int wexc = 0;
    for (int w = 0; w < wave; ++w) wexc += wsh[w];
    if (i < n) out[i] = boff[blockIdx.x] + wexc + x - orig;
}

// ---------------- phase C: per-bucket gather + LDS counting sort by node ----------------

__global__ __launch_bounds__(256) void k_fsort(const uint2* __restrict__ tmps,
                                               const int* __restrict__ lscan,
                                               const int* __restrict__ goff,
                                               int* __restrict__ rowptr,
                                               uint2* __restrict__ edata) {
    __shared__ uint2 ent[FCAP];                  // 44 KB
    __shared__ unsigned short perm[FCAP];        // 11 KB
    __shared__ int joff[NBLK + 1];
    __shared__ int jsrc[NBLK];
    __shared__ int hist[256];
    __shared__ int cur[256];
    const int b = blockIdx.x;
    const int t = threadIdx.x;
    const int base = goff[b * NBLK];             // bucket base position in edata

    for (int q = t; q < 256; q += 256) hist[q] = 0;
    for (int j = t; j < NBLK; j += 256) {
        joff[j] = goff[b * NBLK + j] - base;
        jsrc[j] = j * CHUNK + lscan[j * NB + b];
    }
    if (t == 0) joff[NBLK] = ((b == NB - 1) ? NEDGES : goff[(b + 1) * NBLK]) - base;
    __syncthreads();
    const int T = min(joff[NBLK], FCAP);

    for (int idx = t; idx < T; idx += 256) {
        int lo = 0, hi = NBLK;
        while (hi - lo > 1) { int mid = (lo + hi) >> 1; if (joff[mid] <= idx) lo = mid; else hi = mid; }
        const uint2 e = tmps[jsrc[lo] + (idx - joff[lo])];   // piecewise-coalesced
        ent[idx] = e;
        atomicAdd(&hist[(e.x >> 17) & 255u], 1);
    }
    __syncthreads();

    // exclusive scan hist[0..256) -> cur, wave 0 (64 lanes x 4)
    if (t < 64) {
        int x[4];
        int run = 0;
#pragma unroll
        for (int q = 0; q < 4; ++q) { x[q] = hist[t * 4 + q]; run += x[q]; }
        int inc = run;
#pragma unroll
        for (int o = 1; o < 64; o <<= 1) {
            int u = __shfl_up(inc, o, 64);
            if (t >= o) inc += u;
        }
        int r = inc - run;
#pragma unroll
        for (int q = 0; q < 4; ++q) { cur[t * 4 + q] = r; r += x[q]; }
    }
    __syncthreads();

    {
        const int i = b * 256 + t;
        if (i < NNODES) rowptr[i] = base + cur[t];
    }
    __syncthreads();    // rowptr reads of cur must complete before rank mutation

    for (int idx = t; idx < T; idx += 256) {
        const int d = (int)((ent[idx].x >> 17) & 255u);
        const int r = atomicAdd(&cur[d], 1);
        perm[r] = (unsigned short)idx;
    }
    __syncthreads();
    for (int k = t; k < T; k += 256)
        edata[base + k] = ent[perm[k]];          // coalesced global write
}

// ---------------- MFMA dual GEMM: [XL|XR] = X @ [Wl|Wr] + bias, bf16 in/out ----------------
// Block = 64 rows x 128 cols, full K in LDS. mfma_f32_16x16x32_bf16 fragments:
// A: row=lane&15, k=(lane>>4)*8+j; B: col=lane&15, k=(lane>>4)*8+j;
// D: col=lane&15, row=(lane>>4)*4+reg. Row pad +8 bf16 -> 2-way (free) LDS banks.

template <int K, bool F32IN>
__global__ __launch_bounds__(256) void k_gemm_mfma(const void* __restrict__ Xin,
                                                   const float* __restrict__ Wl,
                                                   const float* __restrict__ bl,
                                                   const float* __restrict__ Wr,
                                                   const float* __restrict__ br,
                                                   unsigned short* __restrict__ XLu,
                                                   unsigned short* __restrict__ XRu) {
    constexpr int KP = K + 8;
    __shared__ unsigned short sA[64 * KP];       // K=128: 17 KB, K=64: 9 KB
    __shared__ unsigned short sB[128 * KP];      // K=128: 34 KB, K=64: 18 KB
    const int t = threadIdx.x;
    const int w = t >> 6, lane = t & 63;
    const int r0 = blockIdx.x * 64;

    // stage B transposed: col-major [col][k]; cols 0-63 = Wl, 64-127 = Wr
    for (int idx = t; idx < K * 64; idx += 256) {
        const int k = idx >> 6, c = idx & 63;
        sB[c * KP + k] = bf16rne(Wl[idx]);
        sB[(64 + c) * KP + k] = bf16rne(Wr[idx]);
    }
    // stage A: 64 rows x K
    if constexpr (F32IN) {
        const float* X = (const float*)Xin;
        for (int idx = t; idx < 64 * (K / 4); idx += 256) {
            const int row = idx / (K / 4), q = idx % (K / 4);
            const int rr = min(r0 + row, NNODES - 1);
            const float4 v = *(const float4*)&X[(size_t)rr * K + q * 4];
            unsigned* p = (unsigned*)&sA[row * KP + q * 4];
            p[0] = pack_bf2(v.x, v.y);
            p[1] = pack_bf2(v.z, v.w);
        }
    } else {
        const uint4* X = (const uint4*)Xin;      // packed bf16 rows: 8 x uint4
        for (int idx = t; idx < 64 * 8; idx += 256) {
            const int row = idx >> 3, q = idx & 7;
            const int rr = min(r0 + row, NNODES - 1);
            *(uint4*)&sA[row * KP + q * 8] = X[(size_t)rr * 8 + q];
        }
    }
    __syncthreads();

    f32x4 acc[8] = {};
    const int mrow = w * 16 + (lane & 15);
    const int kb = (lane >> 4) * 8;
#pragma unroll
    for (int kc = 0; kc < K / 32; ++kc) {
        const bf16x8 af = *(const bf16x8*)&sA[mrow * KP + kc * 32 + kb];
#pragma unroll
        for (int nt = 0; nt < 8; ++nt) {
            const bf16x8 bfr = *(const bf16x8*)&sB[(nt * 16 + (lane & 15)) * KP + kc * 32 + kb];
            acc[nt] = __builtin_amdgcn_mfma_f32_16x16x32_bf16(af, bfr, acc[nt], 0, 0, 0);
        }
    }

    // epilogue: bias + bf16 store (ushort per value; 16-contig runs per quarter-wave)
    const int colL = lane & 15;
    const int rbase = r0 + w * 16 + (lane >> 4) * 4;
#pragma unroll
    for (int nt = 0; nt < 8; ++nt) {
        const int col = nt * 16 + colL;
        const bool isL = col < 64;
        const float bv = isL ? bl[col] : br[col - 64];
        unsigned short* OUT = isL ? XLu : XRu;
        const int oc = isL ? col : col - 64;
#pragma unroll
        for (int r = 0; r < 4; ++r) {
            const int grow = rbase + r;
            if (grow < NNODES)
                OUT[(size_t)grow * 64 + oc] = bf16rne(acc[nt][r] + bv);
        }
    }
}

// ---------------- fused GATv2 edge pass ----------------
// One wave per node. lane = 8*group + fl; group g handles edge e+g (8/batch);
// lane holds features [fl*8, fl*8+8) from one uint4 of packed bf16.
// Fused leaky: att*leaky(m) = 0.6*(att.m) + 0.4*(att.|m|), |m| free modifier.
// Per-wave LDS combine, stride-65 scalar stores, no block barrier.
// Output H packed bf16 (32 uints/node).

__global__ __launch_bounds__(256) void k_edge(const uint4* __restrict__ XLh,
                                              const uint4* __restrict__ XRh,
                                              const int* __restrict__ rowptr,
                                              const uint2* __restrict__ edata,
                                              const float* __restrict__ We,
                                              const float* __restrict__ att,
                                              const float* __restrict__ bias,
                                              const float* __restrict__ easum,
                                              unsigned* __restrict__ Hh) {
    __shared__ float red[4][8][65];              // bank = (g + 8*fl + k) % 32: 2/bank (free)
    const int wave = threadIdx.x >> 6, lane = threadIdx.x & 63;
    const int g = lane >> 3, fl = lane & 7;
    const int fo = fl * 8;
    float We8[8], att8[8];
    *(float4*)&We8[0] = *(const float4*)&We[fo];
    *(float4*)&We8[4] = *(const float4*)&We[fo + 4];
    *(float4*)&att8[0] = *(const float4*)&att[fo];
    *(float4*)&att8[4] = *(const float4*)&att[fo + 4];
    const float bias_l = bias[lane];
    const float ea_mean = easum[0] * (1.0f / NEDGES);

    const int i = blockIdx.x * 4 + wave;         // exact grid: always < NNODES

    float xr8[8], xl8[8], acc8[8];
    unpack_bf8(XRh[(size_t)i * 8 + fl], xr8);
    unpack_bf8(XLh[(size_t)i * 8 + fl], xl8);

    // self-loop (src=i, ea=ea_mean): wave-uniform logit
    {
        float s1 = 0.f, s2 = 0.f;
#pragma unroll
        for (int f = 0; f < 8; ++f) {
            const float m = fmaf(ea_mean, We8[f], xr8[f]) + xl8[f];
            s1 = fmaf(att8[f], m, s1);
            s2 = fmaf(att8[f], fabsf(m), s2);
        }
        float pt = fmaf(0.6f, s1, 0.4f * s2);
        pt += __shfl_xor(pt, 1);
        pt += __shfl_xor(pt, 2);
        pt += __shfl_xor(pt, 4);
        red[wave][0][64] = pt;                   // spare slot broadcast
    }
    float M = red[wave][0][64];
    __builtin_amdgcn_wave_barrier();
    float S = (g == 0) ? 1.f : 0.f;              // per-group partial denominator
#pragma unroll
    for (int f = 0; f < 8; ++f) acc8[f] = (g == 0) ? xl8[f] : 0.f;

    const int e0 = rowptr[i];
    const int ne = rowptr[i + 1] - e0;
    const uint2 z2 = make_uint2(0u, 0u);

    uint2 se = (g < ne) ? edata[e0 + g] : z2;    // meta prefetch, 1 batch ahead
    for (int e = 0; e < ne; e += 8) {
        const uint2 se_cur = se;
        const bool valid = (e + g) < ne;
        if (e + 8 + g < ne) se = edata[e0 + e + 8 + g];
        const int s = (int)(se_cur.x & 0x1FFFFu);
        const float eav = __uint_as_float(se_cur.y);
        float v8[8];
        unpack_bf8(XLh[(size_t)s * 8 + fl], v8);

        float s1 = 0.f, s2 = 0.f;
#pragma unroll
        for (int f = 0; f < 8; ++f) {
            const float m = fmaf(eav, We8[f], xr8[f]) + v8[f];
            s1 = fmaf(att8[f], m, s1);
            s2 = fmaf(att8[f], fabsf(m), s2);
        }
        float d = fmaf(0.6f, s1, 0.4f * s2);
        d += __shfl_xor(d, 1);
        d += __shfl_xor(d, 2);
        d += __shfl_xor(d, 4);                   // group-uniform logit
        const float a = valid ? d : -1e30f;

        if (__any(a > M)) {                      // ballot; wave-uniform branch
            float am = fmaxf(a, __shfl_xor(a, 8));
            am = fmaxf(am, __shfl_xor(am, 16));
            am = fmaxf(am, __shfl_xor(am, 32));
            const float sc = __expf(M - am);     // exact rescale
            S *= sc;
#pragma unroll
            for (int f = 0; f < 8; ++f) acc8[f] *= sc;
            M = am;
        }
        const float p = __expf(a - M);           // 0 for invalid groups
        S += p;                                  // group-partial (deferred reduce)
#pragma unroll
        for (int f = 0; f < 8; ++f) acc8[f] = fmaf(p, v8[f], acc8[f]);
    }

    // reduce S across groups (xor 8/16/32 touches g bits only)
    S += __shfl_xor(S, 8);
    S += __shfl_xor(S, 16);
    S += __shfl_xor(S, 32);

    // per-wave LDS transpose-combine (no inter-wave sharing -> no block barrier)
#pragma unroll
    for (int k = 0; k < 8; ++k) red[wave][g][fo + k] = acc8[k];
    asm volatile("" ::: "memory");
    __builtin_amdgcn_wave_barrier();             // DS ops complete in-order per wave
    float o = 0.f;
#pragma unroll
    for (int gg = 0; gg < 8; ++gg) o += red[wave][gg][lane];
    o = fmaxf(o / S + bias_l, 0.f);              // bias + fused ReLU
    const float on = __shfl_xor(o, 1);
    if (!(lane & 1))
        Hh[(size_t)i * 32 + (lane >> 1)] = pack_bf2(o, on);   // packed bf16 store
}

// ---------------- tail: mean pool + linear + softmax ----------------

__global__ __launch_bounds__(256) void k_colsum(const unsigned* __restrict__ Hh,
                                                float* __restrict__ gsum) {
    const int t = threadIdx.x;
    const int c = t & 31;                        // uint column = feature pair
    const int rl = t >> 5;                       // 0..7
    float s0 = 0.f, s1 = 0.f;
    for (int r = blockIdx.x * 8 + rl; r < NNODES; r += gridDim.x * 8) {
        const unsigned u = Hh[(size_t)r * 32 + c];
        s0 += __uint_as_float(u << 16);
        s1 += __uint_as_float(u & 0xFFFF0000u);
    }
    __shared__ float ls[8][64];
    ls[rl][2 * c] = s0;
    ls[rl][2 * c + 1] = s1;
    __syncthreads();
    if (t < 64) {
        float s = 0.f;
#pragma unroll
        for (int q = 0; q < 8; ++q) s += ls[q][t];
        atomicAdd(&gsum[t], s);
    }
}

__global__ __launch_bounds__(64) void k_head(const float* __restrict__ gsum,
                                             const float* __restrict__ Wlin,
                                             const float* __restrict__ blin,
                                             float* __restrict__ out) {
    int lane = threadIdx.x;
    float g = gsum[lane] * (1.0f / NNODES);
    float a0 = wave_sum64(g * Wlin[lane * 2 + 0]);
    float a1 = wave_sum64(g * Wlin[lane * 2 + 1]);
    if (lane == 0) {
        float l0 = a0 + blin[0], l1 = a1 + blin[1];
        float mx = fmaxf(l0, l1);
        float e0 = __expf(l0 - mx), e1 = __expf(l1 - mx);
        float inv = 1.f / (e0 + e1);
        out[0] = e0 * inv;
        out[1] = e1 * inv;
    }
}

extern "C" void kernel_launch(void* const* d_in, const int* in_sizes, int n_in,
                              void* d_out, int out_size, void* d_ws, size_t ws_size,
                              hipStream_t stream) {
    const float* x = (const float*)d_in[0];
    const int* ei = (const int*)d_in[1];
    const float* ea = (const float*)d_in[2];
    const int* src = ei;
    const int* dst = ei + NEDGES;
    auto W = [&](int i) { return (const float*)d_in[i]; };

    char* ws = (char*)d_ws;
    size_t off = 0;
    auto alloc = [&](size_t bytes) {
        void* p = ws + off;
        off += (bytes + 255) & ~(size_t)255;
        return p;
    };
    unsigned short* XLu = (unsigned short*)alloc((size_t)NNODES * 64 * 2);  // packed bf16
    unsigned short* XRu = (unsigned short*)alloc((size_t)NNODES * 64 * 2);  // packed bf16
    unsigned* Hh = (unsigned*)alloc((size_t)NBLK * CHUNK * 8);  // 12.82 MB: packed bf16 H, aliased by tmps
    int* rowptr = (int*)alloc((size_t)(NNODES + 1) * 4);
    uint2* edata = (uint2*)alloc((size_t)NEDGES * 8);
    float* easum = (float*)alloc(4);
    float* gsum = (float*)alloc(64 * 4);
    int* gcnt = (int*)alloc((size_t)FLATN * 4);
    int* lscan = (int*)alloc((size_t)FLATN * 4);
    int* goff = (int*)alloc((size_t)FLATN * 4);
    int* part2 = (int*)alloc((size_t)SCB * 4);
    int* boff2 = (int*)alloc((size_t)SCB * 4);
    uint2* tmps = (uint2*)Hh;  // Hh dead until layer-1 k_edge; sort uses it first

    hipMemsetAsync(easum, 0, 4, stream);
    hipMemsetAsync(gsum, 0, 64 * 4, stream);

    k_lsort<<<NBLK, 256, 0, stream>>>(src, dst, ea, tmps, gcnt, lscan, easum);
    k_part2<<<SCB, 256, 0, stream>>>(gcnt, FLATN, part2);
    k_scanb2<<<1, 1024, 0, stream>>>(part2, SCB, boff2, rowptr);
    k_scanfin2<<<SCB, 256, 0, stream>>>(gcnt, FLATN, boff2, goff);
    k_fsort<<<NB, 256, 0, stream>>>(tmps, lscan, goff, rowptr, edata);

    int gemm_grid = (NNODES + 63) / 64;   // 1563
    int edge_grid = NNODES / 4;           // exact: one wave per node

    k_gemm_mfma<128, true><<<gemm_grid, 256, 0, stream>>>(x, W(3), W(4), W(5), W(6), XLu, XRu);
    k_edge<<<edge_grid, 256, 0, stream>>>((const uint4*)XLu, (const uint4*)XRu, rowptr, edata,
                                          W(7), W(8), W(9), easum, Hh);
    k_gemm_mfma<64, false><<<gemm_grid, 256, 0, stream>>>(Hh, W(10), W(11), W(12), W(13), XLu, XRu);
    k_edge<<<edge_grid, 256, 0, stream>>>((const uint4*)XLu, (const uint4*)XRu, rowptr, edata,
                                          W(14), W(15), W(16), easum, Hh);
    k_gemm_mfma<64, false><<<gemm_grid, 256, 0, stream>>>(Hh, W(17), W(18), W(19), W(20), XLu, XRu);
    k_edge<<<edge_grid, 256, 0, stream>>>((const uint4*)XLu, (const uint4*)XRu, rowptr, edata,
                                          W(21), W(22), W(23), easum, Hh);

    k_colsum<<<256, 256, 0, stream>>>(Hh, gsum);
    k_head<<<1, 64, 0, stream>>>(gsum, W(24), W(25), (float*)d_out);
}